// Round 14
// baseline (549.696 us; speedup 1.0000x reference)
//
#include <hip/hip_runtime.h>
#include <hip/hip_bf16.h>
#include <math.h>

#define Nn 80000
#define Dd 1000
#define Ee 1280000
#define MM 64000
#define NT 32   // K tiles of 32

typedef __attribute__((ext_vector_type(8))) short bf16x8;
typedef __attribute__((ext_vector_type(4))) float f32x4;

__device__ inline unsigned short f2bf(float f){
  union { float f; unsigned u; } c; c.f = f;
  unsigned u = c.u;
  u += 0x7FFFu + ((u >> 16) & 1u);
  return (unsigned short)(u >> 16);
}
__device__ inline float bf2f(unsigned short s){
  return __uint_as_float(((unsigned)s) << 16);
}

__device__ __forceinline__ void gload16(const void* g, void* l){
  __builtin_amdgcn_global_load_lds(
      (const __attribute__((address_space(1))) void*)g,
      (__attribute__((address_space(3))) void*)l, 16, 0, 0);
}

__device__ __forceinline__ bf16x8 cvt8(f32x4 a, f32x4 b){
  union { __hip_bfloat162 h; unsigned u; } c0, c1, c2, c3;
  c0.h = __float22bfloat162_rn(make_float2(a.x, a.y));
  c1.h = __float22bfloat162_rn(make_float2(a.z, a.w));
  c2.h = __float22bfloat162_rn(make_float2(b.x, b.y));
  c3.h = __float22bfloat162_rn(make_float2(b.z, b.w));
  union { unsigned u[4]; bf16x8 v; } r;
  r.u[0] = c0.u; r.u[1] = c1.u; r.u[2] = c2.u; r.u[3] = c3.u;
  return r.v;
}

// ---- init: Wim compact swizzled B image; WdT2 (1024 rows, zero-padded);
//      tw[97]; zero flags/deg/loss --------------------------------------------
__global__ __launch_bounds__(256) void k_init(const float* __restrict__ W1,
    const float* __restrict__ Wdec, const float* __restrict__ token,
    unsigned short* __restrict__ Wim, unsigned short* __restrict__ WdT2,
    float* __restrict__ tw, int* __restrict__ flags, int* __restrict__ deg,
    float* __restrict__ loss)
{
  int i = blockIdx.x*256 + threadIdx.x;   // grid 665 blocks = 170240 threads
  if (i < 131072){                        // Wim: 32 tiles x 128 rows x 32 bf16
    int t   = i >> 12;
    int rem = i & 4095;
    int c   = rem >> 5;                   // row (col of W) 0..127
    int pos = rem & 31;
    int slot = pos >> 3;                  // 16B unit in LDS
    int j    = pos & 7;
    int u    = slot ^ (c & 3);            // pre-applied swizzle
    int k    = t*32 + u*8 + j;
    float v = 0.f;
    if (c < 96 && k < Dd) v = (c < 64) ? W1[k*64 + c] : Wdec[(size_t)(c-64)*Dd + k];
    Wim[i] = f2bf(v);
  }
  unsigned t1 = (unsigned)(i - 131072);
  if (t1 < 32768u){                       // WdT2[col][k] = Wdec[k][col], col<1024
    int col = t1 >> 5, k = t1 & 31;
    WdT2[t1] = (col < Dd) ? f2bf(Wdec[(size_t)k*Dd + col]) : (unsigned short)0;
  }
  if (i < Nn){ flags[i] = 0; deg[i] = 0; }
  if (i == 0) *loss = 0.f;
  unsigned u3 = (unsigned)(i - 163840);
  if (u3 < 6208u){                        // tw: one wave per output j
    int j = u3 >> 6, l = u3 & 63;
    float s = 0.f;
    if (j < 64){ for (int k = l; k < Dd; k += 64) s += token[k]*W1[k*64 + j]; }
    else if (j < 96){ const float* wr = Wdec + (size_t)(j-64)*Dd;
                      for (int k = l; k < Dd; k += 64) s += token[k]*wr[k]; }
    else { for (int k = l; k < Dd; k += 64) s += token[k]*token[k]; }
    #pragma unroll
    for (int o = 32; o; o >>= 1) s += __shfl_down(s, o);
    if (l == 0) tw[j] = s;
  }
}

// ---- edge bucket fill + flags scatter (separate: bucket lines stay L2-hot) --
__global__ __launch_bounds__(256) void k_fillb(const int* __restrict__ rows,
    const int* __restrict__ cols, const float* __restrict__ vals,
    const int* __restrict__ mask, int* __restrict__ flags,
    int* __restrict__ deg, int2* __restrict__ buck)
{
  int i = blockIdx.x*256 + threadIdx.x;
  if (i < MM) flags[mask[i]] = 1;
  if (i < Ee){
    int r = rows[i];
    int s = atomicAdd(&deg[r], 1);
    if (s < 64){
      int2 pr; pr.x = cols[i]; pr.y = __float_as_int(vals[i]);
      buck[((size_t)r << 6) + s] = pr;
    }
  }
}

// ---- GEMM1 (pure, R10 form): reg-staged bf16 A, 1-deep prefetch, vmcnt(6) --
// LDS: As 0..8192 (bf16 [128][32] swizzled), B0 8192..16384, B1 16384..24576,
//      tokL 24576..28672. Phase2: Hs 0..33792, W2s 33792..37888.
__global__ __launch_bounds__(256, 4) void k_gemm1(
    const float* __restrict__ x, const unsigned short* __restrict__ Wim,
    const int* __restrict__ flags, const float* __restrict__ tw,
    const float* __restrict__ token,
    const float* __restrict__ b1, const float* __restrict__ g1,
    const float* __restrict__ be1, const float* __restrict__ rm1,
    const float* __restrict__ rv1, const float* __restrict__ W2,
    const float* __restrict__ b2, const float* __restrict__ g2,
    const float* __restrict__ be2, const float* __restrict__ rm2,
    const float* __restrict__ rv2, float* __restrict__ fx,
    float* __restrict__ wx, float* __restrict__ sii_node)
{
  __shared__ char smem[37888];
  unsigned short* As = (unsigned short*)smem;
  float* tokL = (float*)(smem + 24576);
  const int tid  = threadIdx.x;
  const int lane = tid & 63;
  const int wave = tid >> 6;
  const int wm = wave >> 1, wn = wave & 1;
  const int l15 = lane & 15, kg = lane >> 4;
  const int row0 = blockIdx.x * 128;

  const int rtid = tid >> 3;              // staging row within group (0..31)
  const int kq   = (tid & 7) * 4;         // k-slice 0,4,..,28
  const int wu   = (kq >> 3) ^ (rtid & 3) ^ ((rtid >> 2) & 3);  // write swizzle
  const int wofs = rtid*32 + wu*8 + (kq & 4);

  const float* xbase = x + (size_t)row0 * Dd;
  f32x4 ra[4];

  for (int i = tid; i < 1024; i += 256) tokL[i] = (i < Dd) ? token[i] : 0.f;

  // prologue: issue A(0), B(0)
  {
    int col = kq;
    #pragma unroll
    for (int j = 0; j < 4; ++j)
      ra[j] = *(const f32x4*)(xbase + (size_t)(j*32 + rtid)*Dd + col);
    const char* wim = (const char*)Wim;
    gload16(wim + (wave*2  )*1024 + lane*16, smem + 8192 + (wave*2  )*1024);
    gload16(wim + (wave*2+1)*1024 + lane*16, smem + 8192 + (wave*2+1)*1024);
  }
  asm volatile("s_waitcnt lgkmcnt(0)" ::: "memory");
  __builtin_amdgcn_s_barrier();           // tokL visible

  const f32x4 zero4 = {0.f,0.f,0.f,0.f};
  f32x4 acc[4][3];
  #pragma unroll
  for (int i = 0; i < 4; ++i){ acc[i][0]=zero4; acc[i][1]=zero4; acc[i][2]=zero4; }
  float sx2[4] = {0.f,0.f,0.f,0.f};
  float sxt[4] = {0.f,0.f,0.f,0.f};

  #pragma unroll 2
  for (int t = 0; t < NT; ++t){
    const char* Bb = smem + 8192 + (t&1)*8192;
    const int k0 = t*32;
    const bool kok = (t < NT-1) || (kq <= 4);
    f32x4 tok4 = *(const f32x4*)(tokL + k0 + kq);

    // stage A(t): cvt once + sii partials + swizzled bf16 ds_write
    #pragma unroll
    for (int j = 0; j < 4; ++j){
      f32x4 v = ra[j];
      if (kok){
        sx2[j] += v.x*v.x + v.y*v.y + v.z*v.z + v.w*v.w;
        sxt[j] += v.x*tok4.x + v.y*tok4.y + v.z*tok4.z + v.w*tok4.w;
      }
      union { __hip_bfloat162 h; unsigned u; } c0, c1;
      c0.h = __float22bfloat162_rn(make_float2(v.x, v.y));
      c1.h = __float22bfloat162_rn(make_float2(v.z, v.w));
      uint2 pk; pk.x = c0.u; pk.y = c1.u;
      *reinterpret_cast<uint2*>(&As[j*1024 + wofs]) = pk;
    }

    // issue A(t+1), B(t+1)
    if (t + 1 < NT){
      int col = k0 + 32 + kq; if (col > 996) col = 996;
      #pragma unroll
      for (int j = 0; j < 4; ++j)
        ra[j] = *(const f32x4*)(xbase + (size_t)(j*32 + rtid)*Dd + col);
      const char* wim = (const char*)Wim + (size_t)(t+1)*8192;
      char* Bn = smem + 8192 + ((t+1)&1)*8192;
      gload16(wim + (wave*2  )*1024 + lane*16, Bn + (wave*2  )*1024);
      gload16(wim + (wave*2+1)*1024 + lane*16, Bn + (wave*2+1)*1024);
      asm volatile("s_waitcnt lgkmcnt(0)" ::: "memory");
      asm volatile("s_waitcnt vmcnt(6)" ::: "memory");
    } else {
      asm volatile("s_waitcnt lgkmcnt(0)" ::: "memory");
      asm volatile("s_waitcnt vmcnt(0)" ::: "memory");
    }
    __builtin_amdgcn_s_barrier();
    __builtin_amdgcn_sched_barrier(0);

    // MFMA phase
    bf16x8 bfr[3];
    #pragma unroll
    for (int ni = 0; ni < 3; ++ni){
      int c = wn*48 + ni*16 + l15;
      bfr[ni] = *(const bf16x8*)(Bb + c*64 + ((kg ^ (c & 3)) << 4));
    }
    const int ru = (kg ^ (l15 & 3) ^ ((l15 >> 2) & 3)) << 4;
    #pragma unroll
    for (int mi = 0; mi < 4; ++mi){
      int r = wm*64 + mi*16 + l15;
      bf16x8 af = *(const bf16x8*)((const char*)As + r*64 + ru);
      acc[mi][0] = __builtin_amdgcn_mfma_f32_16x16x32_bf16(af, bfr[0], acc[mi][0], 0, 0, 0);
      acc[mi][1] = __builtin_amdgcn_mfma_f32_16x16x32_bf16(af, bfr[1], acc[mi][1], 0, 0, 0);
      acc[mi][2] = __builtin_amdgcn_mfma_f32_16x16x32_bf16(af, bfr[2], acc[mi][2], 0, 0, 0);
    }
    __builtin_amdgcn_sched_barrier(0);
    __builtin_amdgcn_s_barrier();
  }

  // sii: 8-thread shfl reduce (threads 8r..8r+7 share a row)
  float stt = tw[96];
  #pragma unroll
  for (int j = 0; j < 4; ++j){
    float a2 = sx2[j], at = sxt[j];
    a2 += __shfl_xor(a2, 1); at += __shfl_xor(at, 1);
    a2 += __shfl_xor(a2, 2); at += __shfl_xor(at, 2);
    a2 += __shfl_xor(a2, 4); at += __shfl_xor(at, 4);
    if ((tid & 7) == 0){
      int row = row0 + j*32 + rtid;
      float fl = flags[row] ? 1.f : 0.f;
      sii_node[row] = a2 + fl*(2.f*at + stt);
    }
  }

  // per-output-row flags
  float flv[4][4];
  #pragma unroll
  for (int mi = 0; mi < 4; ++mi)
    #pragma unroll
    for (int r4 = 0; r4 < 4; ++r4)
      flv[mi][r4] = flags[row0 + wm*64 + mi*16 + (lane>>4)*4 + r4] ? 1.f : 0.f;

  float* Hs  = (float*)smem;
  float* W2s = (float*)(smem + 33792);
  for (int i = tid; i < 1024; i += 256) W2s[i] = W2[i];

  // epilogue: cols <64 -> BN1+ELU into Hs; cols >=64 -> wx
  #pragma unroll
  for (int ni = 0; ni < 3; ++ni){
    int n = wn*48 + ni*16 + l15;
    float twn = tw[n];
    if (n < 64){
      float bb = b1[n], rmv = rm1[n];
      float scv = g1[n]*rsqrtf(rv1[n] + 1e-3f), bev = be1[n];
      #pragma unroll
      for (int mi = 0; mi < 4; ++mi){
        #pragma unroll
        for (int r4 = 0; r4 < 4; ++r4){
          int lrow = wm*64 + mi*16 + (lane>>4)*4 + r4;
          float v = (acc[mi][ni][r4] + flv[mi][r4]*twn + bb - rmv)*scv + bev;
          v = (v > 0.f) ? v : expm1f(v);
          Hs[lrow*66 + n] = v;
        }
      }
    } else {
      int j = n - 64;
      #pragma unroll
      for (int mi = 0; mi < 4; ++mi){
        #pragma unroll
        for (int r4 = 0; r4 < 4; ++r4){
          int lrow = wm*64 + mi*16 + (lane>>4)*4 + r4;
          wx[(size_t)(row0 + lrow)*32 + j] = acc[mi][ni][r4] + flv[mi][r4]*twn;
        }
      }
    }
  }
  __syncthreads();

  // phase 2: fx = elu(bn2(Hs @ W2 + b2))
  {
    int j = tid & 15;
    float pb = b2[j], prm = rm2[j];
    float psc = g2[j]*rsqrtf(rv2[j] + 1e-3f), pbe = be2[j];
    int rb = (tid >> 4) * 8;
    #pragma unroll
    for (int rr = 0; rr < 8; ++rr){
      int r = rb + rr;
      float a = pb;
      #pragma unroll
      for (int k = 0; k < 64; ++k) a += Hs[r*66 + k]*W2s[k*16 + j];
      float v = (a - prm)*psc + pbe;
      v = (v > 0.f) ? v : expm1f(v);
      fx[(size_t)(row0 + r)*16 + j] = v;
    }
  }
}

// ---- SpMM F=16 over buckets + fused h1 = relu(row @ Wgc1) -> bf16 -----------
__global__ __launch_bounds__(256) void k_spmm16(const int* __restrict__ deg,
    const int2* __restrict__ buck, const float* __restrict__ in,
    float* __restrict__ out, const float* __restrict__ Wgc1,
    unsigned short* __restrict__ h1b)
{
  __shared__ float Ws[1024];
  for (int t = threadIdx.x; t < 1024; t += 256) Ws[t] = Wgc1[t];
  __syncthreads();
  int row = blockIdx.x*16 + (threadIdx.x >> 4);
  int l = threadIdx.x & 15;
  int d = deg[row]; if (d > 64) d = 64;
  const int2* bp = buck + ((size_t)row << 6);
  float acc = 0.f;
  for (int p = 0; p < d; ++p){
    int2 ce = bp[p];
    acc += __int_as_float(ce.y) * in[(size_t)ce.x*16 + l];
  }
  out[(size_t)row*16 + l] = acc;
  float h0=0.f, h1=0.f, h2=0.f, h3=0.f;
  #pragma unroll
  for (int k = 0; k < 16; ++k){
    float av = __shfl(acc, k, 16);
    const float* wp = &Ws[k*64 + l*4];
    h0 += av*wp[0]; h1 += av*wp[1]; h2 += av*wp[2]; h3 += av*wp[3];
  }
  ushort4 pk;
  pk.x = f2bf(fmaxf(h0, 0.f)); pk.y = f2bf(fmaxf(h1, 0.f));
  pk.z = f2bf(fmaxf(h2, 0.f)); pk.w = f2bf(fmaxf(h3, 0.f));
  *reinterpret_cast<ushort4*>(&h1b[(size_t)row*64 + l*4]) = pk;
}

// ---- GCN2: 16 rows/block; ah = A@h1 (bf16 gather), mu/lv/z/gz, fused q ------
__global__ __launch_bounds__(256) void k_gcn2(const int* __restrict__ deg,
    const int2* __restrict__ buck, const unsigned short* __restrict__ h1b,
    const float* __restrict__ Wgc2, const float* __restrict__ Wgc3,
    const float* __restrict__ fx, const float* __restrict__ cl,
    float* __restrict__ z, float* __restrict__ mu,
    float* __restrict__ lv, float* __restrict__ gz, float* __restrict__ q)
{
  __shared__ float ah[16][65];
  __shared__ float Ws[2048];
  __shared__ float cls[320];
  __shared__ float zs[16][33];
  __shared__ float qv[16][10];
  int t = threadIdx.x;
  for (int i = t; i < 1024; i += 256){ Ws[i] = Wgc2[i]; Ws[1024 + i] = Wgc3[i]; }
  for (int i = t; i < 320; i += 256) cls[i] = cl[i];
  const int wave = t >> 6, lane = t & 63;
  const int row0 = blockIdx.x*16;
  #pragma unroll
  for (int rr = 0; rr < 4; ++rr){
    int lr = wave*4 + rr;
    int row = row0 + lr;
    int d = deg[row]; if (d > 64) d = 64;
    const int2* bp = buck + ((size_t)row << 6);
    float acc = 0.f;
    for (int p = 0; p < d; ++p){
      int2 ce = bp[p];
      acc += __int_as_float(ce.y) * bf2f(h1b[(size_t)ce.x*64 + lane]);
    }
    ah[lr][lane] = acc;
  }
  __syncthreads();
  {
    int r = t >> 4, j = t & 15;
    const float* ar = ah[r];
    float m = 0.f, l = 0.f;
    #pragma unroll 16
    for (int k = 0; k < 64; ++k){
      float a = ar[k];
      m += a*Ws[k*16 + j];
      l += a*Ws[1024 + k*16 + j];
    }
    size_t grow = (size_t)(row0 + r);
    mu[grow*16 + j] = m;
    gz[grow*16 + j] = m;
    z[grow*32 + 16 + j] = m;
    zs[r][16 + j] = m;
    lv[grow*16 + j] = l;
    float v = fx[grow*16 + j];
    z[grow*32 + j] = v;
    zs[r][j] = v;
  }
  __syncthreads();
  if (t < 160){
    int r = t / 10, c = t - r*10;
    float d2 = 0.f;
    #pragma unroll
    for (int k = 0; k < 32; ++k){ float d = zs[r][k] - cls[c*32 + k]; d2 += d*d; }
    qv[r][c] = 1.f/(1.f + d2);
  }
  __syncthreads();
  if (t < 160){
    int r = t / 10, c = t - r*10;
    float ss = 0.f;
    #pragma unroll
    for (int cc = 0; cc < 10; ++cc) ss += qv[r][cc];
    q[(size_t)(row0 + r)*10 + c] = qv[r][c]/ss;
  }
}

// ---- decoder: inline amu gather + MFMA + LDS-bounce full-line stores
//      + fused masked loss (round-10 proven form) -----------------------------
__global__ __launch_bounds__(256) void k_dec(const float* __restrict__ afx,
    const float* __restrict__ mu, const int* __restrict__ deg,
    const int2* __restrict__ buck, const unsigned short* __restrict__ WdT2,
    const float* __restrict__ wx, const float* __restrict__ sii_node,
    const int* __restrict__ flags, float* __restrict__ de,
    float* __restrict__ loss)
{
  __shared__ float stg[4][16][68];
  __shared__ float amuL[64][17];
  __shared__ float bsum[4];
  const int tid  = threadIdx.x;
  const int lane = tid & 63;
  const int wave = tid >> 6;
  const int base = blockIdx.x*64;

  // inline amu = A@mu for this block's 64 rows (16 rows x 16 lanes per pass)
  {
    int l = tid & 15, rg = tid >> 4;
    #pragma unroll
    for (int pass = 0; pass < 4; ++pass){
      int lr = pass*16 + rg;
      int row = base + lr;
      int d = deg[row]; if (d > 64) d = 64;
      const int2* bp = buck + ((size_t)row << 6);
      float acc = 0.f;
      for (int p = 0; p < d; ++p){
        int2 ce = bp[p];
        acc += __int_as_float(ce.y) * mu[(size_t)ce.x*16 + l];
      }
      amuL[lr][l] = acc;
    }
  }
  __syncthreads();

  const int r0 = base + wave*16;
  const int kg = lane >> 4;
  const int l15 = lane & 15;
  const int row = r0 + l15;
  f32x4 a0, a1;
  if (kg < 2){
    const float* asrc = afx + (size_t)row*16 + kg*8;
    a0 = *reinterpret_cast<const f32x4*>(asrc);
    a1 = *reinterpret_cast<const f32x4*>(asrc + 4);
  } else {
    const float* asrc = &amuL[wave*16 + l15][(kg-2)*8];
    a0 = *reinterpret_cast<const f32x4*>(asrc);
    a1 = *reinterpret_cast<const f32x4*>(asrc + 4);
  }
  bf16x8 af = cvt8(a0, a1);            // B-operand: az row (col of D-tile)
  const float* wsrc = wx + (size_t)row*32 + kg*8;
  f32x4 w0 = *reinterpret_cast<const f32x4*>(wsrc);
  f32x4 w1 = *reinterpret_cast<const f32x4*>(wsrc + 4);
  float sri = a0.x*w0.x + a0.y*w0.y + a0.z*w0.z + a0.w*w0.w
            + a1.x*w1.x + a1.y*w1.y + a1.z*w1.z + a1.w*w1.w;

  const f32x4 zero4 = {0.f,0.f,0.f,0.f};
  float sq = 0.f;
  float (*S)[68] = stg[wave];
  const int srow = lane >> 4;            // 4 rows per store instr
  const int scol = l15*4;                // 16B segment within 64-col group

  for (int g = 0; g < 16; ++g){          // 16 groups of 64 cols (0..1023)
    int c0 = g*64;
    #pragma unroll
    for (int j = 0; j < 4; ++j){
      int cb = c0 + j*16;
      bf16x8 bf = *reinterpret_cast<const bf16x8*>(&WdT2[(size_t)(cb + l15)*32 + kg*8]);
      // A-operand = Wdec^T frag; cols >=1000 are zero rows -> d = 0 (sq safe)
      f32x4 d = __builtin_amdgcn_mfma_f32_16x16x32_bf16(bf, af, zero4, 0, 0, 0);
      sq += d[0]*d[0] + d[1]*d[1] + d[2]*d[2] + d[3]*d[3];
      *reinterpret_cast<f32x4*>(&S[l15][j*16 + kg*4]) = d;
    }
    asm volatile("s_waitcnt lgkmcnt(0)" ::: "memory");
    __builtin_amdgcn_sched_barrier(0);
    #pragma unroll
    for (int sub = 0; sub < 4; ++sub){
      int lr = sub*4 + srow;
      int cc = c0 + scol;
      if (cc < Dd){
        f32x4 v = *reinterpret_cast<const f32x4*>(&S[lr][scol]);
        *reinterpret_cast<f32x4*>(&de[(size_t)(r0 + lr)*Dd + cc]) = v;
      }
    }
    __builtin_amdgcn_sched_barrier(0);
    asm volatile("s_waitcnt lgkmcnt(0)" ::: "memory");   // reads done before rewrite
  }
  sq  += __shfl_xor(sq, 16);  sq  += __shfl_xor(sq, 32);
  sri += __shfl_xor(sri, 16); sri += __shfl_xor(sri, 32);
  float tval = 0.f;
  if (kg == 0){
    float nr = fmaxf(sqrtf(sq), 1e-12f);
    float ni = fmaxf(sqrtf(sii_node[row]), 1e-12f);
    float tt = 1.f - sri/(nr*ni);
    tval = flags[row] ? tt*tt*tt : 0.f;
  }
  #pragma unroll
  for (int o = 1; o < 16; o <<= 1) tval += __shfl_xor(tval, o);
  if (lane == 0) bsum[wave] = tval;
  __syncthreads();
  if (tid == 0)
    atomicAdd(loss, (bsum[0] + bsum[1] + bsum[2] + bsum[3]) * (1.f/MM));
}

// ---- launch ------------------------------------------------------------------
extern "C" void kernel_launch(void* const* d_in, const int* in_sizes, int n_in,
                              void* d_out, int out_size, void* d_ws, size_t ws_size,
                              hipStream_t stream)
{
  const float* x     = (const float*)d_in[0];
  const int*   erow  = (const int*)  d_in[1];
  const int*   ecol  = (const int*)  d_in[2];
  const float* evls  = (const float*)d_in[3];
  const int*   mask  = (const int*)  d_in[4];
  const float* token = (const float*)d_in[5];
  const float* W1  = (const float*)d_in[6];
  const float* b1  = (const float*)d_in[7];
  const float* g1  = (const float*)d_in[8];
  const float* be1 = (const float*)d_in[9];
  const float* rm1 = (const float*)d_in[10];
  const float* rv1 = (const float*)d_in[11];
  const float* W2  = (const float*)d_in[12];
  const float* b2  = (const float*)d_in[13];
  const float* g2  = (const float*)d_in[14];
  const float* be2 = (const float*)d_in[15];
  const float* rm2 = (const float*)d_in[16];
  const float* rv2 = (const float*)d_in[17];
  const float* Wgc1= (const float*)d_in[18];
  const float* Wgc2= (const float*)d_in[19];
  const float* Wgc3= (const float*)d_in[20];
  const float* Wdec= (const float*)d_in[21];
  const float* clus= (const float*)d_in[22];

  float* out = (float*)d_out;
  float* oz  = out;
  float* omu = out + (size_t)Nn*32;
  float* olv = omu + (size_t)Nn*16;
  float* ode = olv + (size_t)Nn*16;
  float* oq  = ode + (size_t)Nn*1000;
  float* ofx = oq  + (size_t)Nn*10;
  float* ogz = ofx + (size_t)Nn*16;
  float* olo = ogz + (size_t)Nn*16;

  char* w = (char*)d_ws;
  unsigned short* Wim  = (unsigned short*)w; w += (size_t)262144;      // 32*128*32*2
  unsigned short* WdT2 = (unsigned short*)w; w += (size_t)65536;       // 1024*32*2
  float* tw    = (float*)w; w += 512;
  int* flags   = (int*)w;   w += (size_t)Nn*4;
  int* deg     = (int*)w;   w += (size_t)Nn*4;
  int2* buck   = (int2*)w;  w += (size_t)Nn*64*8;                      // 41 MB
  float* afx   = (float*)w; w += (size_t)Nn*16*4;
  unsigned short* h1b = (unsigned short*)w; w += (size_t)Nn*64*2;
  float* wx    = (float*)w; w += (size_t)Nn*32*4;
  float* sii   = (float*)w; w += (size_t)Nn*4;

  k_init<<<dim3(665), dim3(256), 0, stream>>>(W1, Wdec, token, Wim, WdT2, tw,
      flags, deg, olo);
  k_fillb<<<dim3((Ee+255)/256), dim3(256), 0, stream>>>(erow, ecol, evls, mask,
      flags, deg, buck);
  k_gemm1<<<dim3(625), dim3(256), 0, stream>>>(x, Wim, flags, tw, token,
      b1, g1, be1, rm1, rv1, W2, b2, g2, be2, rm2, rv2, ofx, wx, sii);
  k_spmm16<<<dim3(Nn/16), dim3(256), 0, stream>>>(deg, buck, ofx, afx, Wgc1, h1b);
  k_gcn2<<<dim3(Nn/16), dim3(256), 0, stream>>>(deg, buck, h1b, Wgc2, Wgc3,
      ofx, clus, oz, omu, olv, ogz, oq);
  k_dec<<<dim3(Nn/64), dim3(256), 0, stream>>>(afx, omu, deg, buck, WdT2,
      wx, sii, flags, ode, olo);
}

// Round 15
// 524.385 us; speedup vs baseline: 1.0483x; 1.0483x over previous
//
#include <hip/hip_runtime.h>
#include <hip/hip_bf16.h>
#include <math.h>

#define Nn 80000
#define Dd 1000
#define Ee 1280000
#define MM 64000
#define NT 32   // K tiles of 32

typedef __attribute__((ext_vector_type(8))) short bf16x8;
typedef __attribute__((ext_vector_type(4))) float f32x4;

__device__ inline unsigned short f2bf(float f){
  union { float f; unsigned u; } c; c.f = f;
  unsigned u = c.u;
  u += 0x7FFFu + ((u >> 16) & 1u);
  return (unsigned short)(u >> 16);
}
__device__ inline float bf2f(unsigned short s){
  return __uint_as_float(((unsigned)s) << 16);
}

__device__ __forceinline__ void gload16(const void* g, void* l){
  __builtin_amdgcn_global_load_lds(
      (const __attribute__((address_space(1))) void*)g,
      (__attribute__((address_space(3))) void*)l, 16, 0, 0);
}

__device__ __forceinline__ bf16x8 cvt8(f32x4 a, f32x4 b){
  union { __hip_bfloat162 h; unsigned u; } c0, c1, c2, c3;
  c0.h = __float22bfloat162_rn(make_float2(a.x, a.y));
  c1.h = __float22bfloat162_rn(make_float2(a.z, a.w));
  c2.h = __float22bfloat162_rn(make_float2(b.x, b.y));
  c3.h = __float22bfloat162_rn(make_float2(b.z, b.w));
  union { unsigned u[4]; bf16x8 v; } r;
  r.u[0] = c0.u; r.u[1] = c1.u; r.u[2] = c2.u; r.u[3] = c3.u;
  return r.v;
}

// ---- init: Wim compact swizzled B image; WdT2 (1024 rows, zero-padded);
//      tw[97]; zero flags/deg/loss --------------------------------------------
__global__ __launch_bounds__(256) void k_init(const float* __restrict__ W1,
    const float* __restrict__ Wdec, const float* __restrict__ token,
    unsigned short* __restrict__ Wim, unsigned short* __restrict__ WdT2,
    float* __restrict__ tw, int* __restrict__ flags, int* __restrict__ deg,
    float* __restrict__ loss)
{
  int i = blockIdx.x*256 + threadIdx.x;   // grid 665 blocks = 170240 threads
  if (i < 131072){                        // Wim: 32 tiles x 128 rows x 32 bf16
    int t   = i >> 12;
    int rem = i & 4095;
    int c   = rem >> 5;                   // row (col of W) 0..127
    int pos = rem & 31;
    int slot = pos >> 3;                  // 16B unit in LDS
    int j    = pos & 7;
    int u    = slot ^ (c & 3);            // pre-applied swizzle
    int k    = t*32 + u*8 + j;
    float v = 0.f;
    if (c < 96 && k < Dd) v = (c < 64) ? W1[k*64 + c] : Wdec[(size_t)(c-64)*Dd + k];
    Wim[i] = f2bf(v);
  }
  unsigned t1 = (unsigned)(i - 131072);
  if (t1 < 32768u){                       // WdT2[col][k] = Wdec[k][col], col<1024
    int col = t1 >> 5, k = t1 & 31;
    WdT2[t1] = (col < Dd) ? f2bf(Wdec[(size_t)k*Dd + col]) : (unsigned short)0;
  }
  if (i < Nn){ flags[i] = 0; deg[i] = 0; }
  if (i == 0) *loss = 0.f;
  unsigned u3 = (unsigned)(i - 163840);
  if (u3 < 6208u){                        // tw: one wave per output j
    int j = u3 >> 6, l = u3 & 63;
    float s = 0.f;
    if (j < 64){ for (int k = l; k < Dd; k += 64) s += token[k]*W1[k*64 + j]; }
    else if (j < 96){ const float* wr = Wdec + (size_t)(j-64)*Dd;
                      for (int k = l; k < Dd; k += 64) s += token[k]*wr[k]; }
    else { for (int k = l; k < Dd; k += 64) s += token[k]*token[k]; }
    #pragma unroll
    for (int o = 32; o; o >>= 1) s += __shfl_down(s, o);
    if (l == 0) tw[j] = s;
  }
}

// ---- flags scatter (must precede fused gemm which reads flags) --------------
__global__ __launch_bounds__(256) void k_flags(const int* __restrict__ mask,
    int* __restrict__ flags)
{
  int i = blockIdx.x*256 + threadIdx.x;
  if (i < MM) flags[mask[i]] = 1;
}

// ---- FUSED: blocks 0..624 = GEMM1 (reg-staged bf16 A, 1-deep prefetch);
//      blocks 625.. = edge bucket fill (rides gemm1's idle memory slots) ------
// LDS: As 0..8192 (bf16 [128][32] swizzled), B0 8192..16384, B1 16384..24576,
//      tokL 24576..28672. Phase2: Hs 0..33792, W2s 33792..37888.
__global__ __launch_bounds__(256, 4) void k_gemm1(
    const float* __restrict__ x, const unsigned short* __restrict__ Wim,
    const int* __restrict__ flags, const float* __restrict__ tw,
    const float* __restrict__ token,
    const float* __restrict__ b1, const float* __restrict__ g1,
    const float* __restrict__ be1, const float* __restrict__ rm1,
    const float* __restrict__ rv1, const float* __restrict__ W2,
    const float* __restrict__ b2, const float* __restrict__ g2,
    const float* __restrict__ be2, const float* __restrict__ rm2,
    const float* __restrict__ rv2, float* __restrict__ fx,
    float* __restrict__ wx, float* __restrict__ sii_node,
    const int* __restrict__ erow, const int* __restrict__ ecol,
    const float* __restrict__ evls, int* __restrict__ deg,
    int2* __restrict__ buck)
{
  __shared__ char smem[37888];
  if (blockIdx.x >= 625){                 // ---- edge-fill path ----
    int i = (blockIdx.x - 625)*256 + threadIdx.x;
    if (i < Ee){
      int r = erow[i];
      int s = atomicAdd(&deg[r], 1);
      if (s < 64){
        int2 pr; pr.x = ecol[i]; pr.y = __float_as_int(evls[i]);
        buck[((size_t)r << 6) + s] = pr;
      }
    }
    return;
  }
  // ---- GEMM path ----
  unsigned short* As = (unsigned short*)smem;
  float* tokL = (float*)(smem + 24576);
  const int tid  = threadIdx.x;
  const int lane = tid & 63;
  const int wave = tid >> 6;
  const int wm = wave >> 1, wn = wave & 1;
  const int l15 = lane & 15, kg = lane >> 4;
  const int row0 = blockIdx.x * 128;

  const int rtid = tid >> 3;              // staging row within group (0..31)
  const int kq   = (tid & 7) * 4;         // k-slice 0,4,..,28
  const int wu   = (kq >> 3) ^ (rtid & 3) ^ ((rtid >> 2) & 3);  // write swizzle
  const int wofs = rtid*32 + wu*8 + (kq & 4);

  const float* xbase = x + (size_t)row0 * Dd;
  f32x4 ra[4];

  for (int i = tid; i < 1024; i += 256) tokL[i] = (i < Dd) ? token[i] : 0.f;

  // prologue: issue A(0), B(0)
  {
    int col = kq;
    #pragma unroll
    for (int j = 0; j < 4; ++j)
      ra[j] = *(const f32x4*)(xbase + (size_t)(j*32 + rtid)*Dd + col);
    const char* wim = (const char*)Wim;
    gload16(wim + (wave*2  )*1024 + lane*16, smem + 8192 + (wave*2  )*1024);
    gload16(wim + (wave*2+1)*1024 + lane*16, smem + 8192 + (wave*2+1)*1024);
  }
  asm volatile("s_waitcnt lgkmcnt(0)" ::: "memory");
  __builtin_amdgcn_s_barrier();           // tokL visible

  const f32x4 zero4 = {0.f,0.f,0.f,0.f};
  f32x4 acc[4][3];
  #pragma unroll
  for (int i = 0; i < 4; ++i){ acc[i][0]=zero4; acc[i][1]=zero4; acc[i][2]=zero4; }
  float sx2[4] = {0.f,0.f,0.f,0.f};
  float sxt[4] = {0.f,0.f,0.f,0.f};

  #pragma unroll 2
  for (int t = 0; t < NT; ++t){
    const char* Bb = smem + 8192 + (t&1)*8192;
    const int k0 = t*32;
    const bool kok = (t < NT-1) || (kq <= 4);
    f32x4 tok4 = *(const f32x4*)(tokL + k0 + kq);

    // stage A(t): cvt once + sii partials + swizzled bf16 ds_write
    #pragma unroll
    for (int j = 0; j < 4; ++j){
      f32x4 v = ra[j];
      if (kok){
        sx2[j] += v.x*v.x + v.y*v.y + v.z*v.z + v.w*v.w;
        sxt[j] += v.x*tok4.x + v.y*tok4.y + v.z*tok4.z + v.w*tok4.w;
      }
      union { __hip_bfloat162 h; unsigned u; } c0, c1;
      c0.h = __float22bfloat162_rn(make_float2(v.x, v.y));
      c1.h = __float22bfloat162_rn(make_float2(v.z, v.w));
      uint2 pk; pk.x = c0.u; pk.y = c1.u;
      *reinterpret_cast<uint2*>(&As[j*1024 + wofs]) = pk;
    }

    // issue A(t+1), B(t+1)
    if (t + 1 < NT){
      int col = k0 + 32 + kq; if (col > 996) col = 996;
      #pragma unroll
      for (int j = 0; j < 4; ++j)
        ra[j] = *(const f32x4*)(xbase + (size_t)(j*32 + rtid)*Dd + col);
      const char* wim = (const char*)Wim + (size_t)(t+1)*8192;
      char* Bn = smem + 8192 + ((t+1)&1)*8192;
      gload16(wim + (wave*2  )*1024 + lane*16, Bn + (wave*2  )*1024);
      gload16(wim + (wave*2+1)*1024 + lane*16, Bn + (wave*2+1)*1024);
      asm volatile("s_waitcnt lgkmcnt(0)" ::: "memory");
      asm volatile("s_waitcnt vmcnt(6)" ::: "memory");
    } else {
      asm volatile("s_waitcnt lgkmcnt(0)" ::: "memory");
      asm volatile("s_waitcnt vmcnt(0)" ::: "memory");
    }
    __builtin_amdgcn_s_barrier();
    __builtin_amdgcn_sched_barrier(0);

    // MFMA phase
    bf16x8 bfr[3];
    #pragma unroll
    for (int ni = 0; ni < 3; ++ni){
      int c = wn*48 + ni*16 + l15;
      bfr[ni] = *(const bf16x8*)(Bb + c*64 + ((kg ^ (c & 3)) << 4));
    }
    const int ru = (kg ^ (l15 & 3) ^ ((l15 >> 2) & 3)) << 4;
    #pragma unroll
    for (int mi = 0; mi < 4; ++mi){
      int r = wm*64 + mi*16 + l15;
      bf16x8 af = *(const bf16x8*)((const char*)As + r*64 + ru);
      acc[mi][0] = __builtin_amdgcn_mfma_f32_16x16x32_bf16(af, bfr[0], acc[mi][0], 0, 0, 0);
      acc[mi][1] = __builtin_amdgcn_mfma_f32_16x16x32_bf16(af, bfr[1], acc[mi][1], 0, 0, 0);
      acc[mi][2] = __builtin_amdgcn_mfma_f32_16x16x32_bf16(af, bfr[2], acc[mi][2], 0, 0, 0);
    }
    __builtin_amdgcn_sched_barrier(0);
    __builtin_amdgcn_s_barrier();
  }

  // sii: 8-thread shfl reduce (threads 8r..8r+7 share a row)
  float stt = tw[96];
  #pragma unroll
  for (int j = 0; j < 4; ++j){
    float a2 = sx2[j], at = sxt[j];
    a2 += __shfl_xor(a2, 1); at += __shfl_xor(at, 1);
    a2 += __shfl_xor(a2, 2); at += __shfl_xor(at, 2);
    a2 += __shfl_xor(a2, 4); at += __shfl_xor(at, 4);
    if ((tid & 7) == 0){
      int row = row0 + j*32 + rtid;
      float fl = flags[row] ? 1.f : 0.f;
      sii_node[row] = a2 + fl*(2.f*at + stt);
    }
  }

  // per-output-row flags
  float flv[4][4];
  #pragma unroll
  for (int mi = 0; mi < 4; ++mi)
    #pragma unroll
    for (int r4 = 0; r4 < 4; ++r4)
      flv[mi][r4] = flags[row0 + wm*64 + mi*16 + (lane>>4)*4 + r4] ? 1.f : 0.f;

  float* Hs  = (float*)smem;
  float* W2s = (float*)(smem + 33792);
  for (int i = tid; i < 1024; i += 256) W2s[i] = W2[i];

  // epilogue: cols <64 -> BN1+ELU into Hs; cols >=64 -> wx
  #pragma unroll
  for (int ni = 0; ni < 3; ++ni){
    int n = wn*48 + ni*16 + l15;
    float twn = tw[n];
    if (n < 64){
      float bb = b1[n], rmv = rm1[n];
      float scv = g1[n]*rsqrtf(rv1[n] + 1e-3f), bev = be1[n];
      #pragma unroll
      for (int mi = 0; mi < 4; ++mi){
        #pragma unroll
        for (int r4 = 0; r4 < 4; ++r4){
          int lrow = wm*64 + mi*16 + (lane>>4)*4 + r4;
          float v = (acc[mi][ni][r4] + flv[mi][r4]*twn + bb - rmv)*scv + bev;
          v = (v > 0.f) ? v : expm1f(v);
          Hs[lrow*66 + n] = v;
        }
      }
    } else {
      int j = n - 64;
      #pragma unroll
      for (int mi = 0; mi < 4; ++mi){
        #pragma unroll
        for (int r4 = 0; r4 < 4; ++r4){
          int lrow = wm*64 + mi*16 + (lane>>4)*4 + r4;
          wx[(size_t)(row0 + lrow)*32 + j] = acc[mi][ni][r4] + flv[mi][r4]*twn;
        }
      }
    }
  }
  __syncthreads();

  // phase 2: fx = elu(bn2(Hs @ W2 + b2))
  {
    int j = tid & 15;
    float pb = b2[j], prm = rm2[j];
    float psc = g2[j]*rsqrtf(rv2[j] + 1e-3f), pbe = be2[j];
    int rb = (tid >> 4) * 8;
    #pragma unroll
    for (int rr = 0; rr < 8; ++rr){
      int r = rb + rr;
      float a = pb;
      #pragma unroll
      for (int k = 0; k < 64; ++k) a += Hs[r*66 + k]*W2s[k*16 + j];
      float v = (a - prm)*psc + pbe;
      v = (v > 0.f) ? v : expm1f(v);
      fx[(size_t)(row0 + r)*16 + j] = v;
    }
  }
}

// ---- SpMM F=16 over buckets + fused h1 = relu(row @ Wgc1) -> bf16 -----------
__global__ __launch_bounds__(256) void k_spmm16(const int* __restrict__ deg,
    const int2* __restrict__ buck, const float* __restrict__ in,
    float* __restrict__ out, const float* __restrict__ Wgc1,
    unsigned short* __restrict__ h1b)
{
  __shared__ float Ws[1024];
  for (int t = threadIdx.x; t < 1024; t += 256) Ws[t] = Wgc1[t];
  __syncthreads();
  int row = blockIdx.x*16 + (threadIdx.x >> 4);
  int l = threadIdx.x & 15;
  int d = deg[row]; if (d > 64) d = 64;
  const int2* bp = buck + ((size_t)row << 6);
  float acc = 0.f;
  for (int p = 0; p < d; ++p){
    int2 ce = bp[p];
    acc += __int_as_float(ce.y) * in[(size_t)ce.x*16 + l];
  }
  out[(size_t)row*16 + l] = acc;
  float h0=0.f, h1=0.f, h2=0.f, h3=0.f;
  #pragma unroll
  for (int k = 0; k < 16; ++k){
    float av = __shfl(acc, k, 16);
    const float* wp = &Ws[k*64 + l*4];
    h0 += av*wp[0]; h1 += av*wp[1]; h2 += av*wp[2]; h3 += av*wp[3];
  }
  ushort4 pk;
  pk.x = f2bf(fmaxf(h0, 0.f)); pk.y = f2bf(fmaxf(h1, 0.f));
  pk.z = f2bf(fmaxf(h2, 0.f)); pk.w = f2bf(fmaxf(h3, 0.f));
  *reinterpret_cast<ushort4*>(&h1b[(size_t)row*64 + l*4]) = pk;
}

// ---- GCN2: 16 rows/block; ah = A@h1 (bf16 gather), mu/lv/z/gz, fused q ------
__global__ __launch_bounds__(256) void k_gcn2(const int* __restrict__ deg,
    const int2* __restrict__ buck, const unsigned short* __restrict__ h1b,
    const float* __restrict__ Wgc2, const float* __restrict__ Wgc3,
    const float* __restrict__ fx, const float* __restrict__ cl,
    float* __restrict__ z, float* __restrict__ mu,
    float* __restrict__ lv, float* __restrict__ gz, float* __restrict__ q)
{
  __shared__ float ah[16][65];
  __shared__ float Ws[2048];
  __shared__ float cls[320];
  __shared__ float zs[16][33];
  __shared__ float qv[16][10];
  int t = threadIdx.x;
  for (int i = t; i < 1024; i += 256){ Ws[i] = Wgc2[i]; Ws[1024 + i] = Wgc3[i]; }
  for (int i = t; i < 320; i += 256) cls[i] = cl[i];
  const int wave = t >> 6, lane = t & 63;
  const int row0 = blockIdx.x*16;
  #pragma unroll
  for (int rr = 0; rr < 4; ++rr){
    int lr = wave*4 + rr;
    int row = row0 + lr;
    int d = deg[row]; if (d > 64) d = 64;
    const int2* bp = buck + ((size_t)row << 6);
    float acc = 0.f;
    for (int p = 0; p < d; ++p){
      int2 ce = bp[p];
      acc += __int_as_float(ce.y) * bf2f(h1b[(size_t)ce.x*64 + lane]);
    }
    ah[lr][lane] = acc;
  }
  __syncthreads();
  {
    int r = t >> 4, j = t & 15;
    const float* ar = ah[r];
    float m = 0.f, l = 0.f;
    #pragma unroll 16
    for (int k = 0; k < 64; ++k){
      float a = ar[k];
      m += a*Ws[k*16 + j];
      l += a*Ws[1024 + k*16 + j];
    }
    size_t grow = (size_t)(row0 + r);
    mu[grow*16 + j] = m;
    gz[grow*16 + j] = m;
    z[grow*32 + 16 + j] = m;
    zs[r][16 + j] = m;
    lv[grow*16 + j] = l;
    float v = fx[grow*16 + j];
    z[grow*32 + j] = v;
    zs[r][j] = v;
  }
  __syncthreads();
  if (t < 160){
    int r = t / 10, c = t - r*10;
    float d2 = 0.f;
    #pragma unroll
    for (int k = 0; k < 32; ++k){ float d = zs[r][k] - cls[c*32 + k]; d2 += d*d; }
    qv[r][c] = 1.f/(1.f + d2);
  }
  __syncthreads();
  if (t < 160){
    int r = t / 10, c = t - r*10;
    float ss = 0.f;
    #pragma unroll
    for (int cc = 0; cc < 10; ++cc) ss += qv[r][cc];
    q[(size_t)(row0 + r)*10 + c] = qv[r][c]/ss;
  }
}

// ---- decoder: inline amu gather + MFMA + double-buffered LDS bounce ->
//      full-line stores + fused masked loss -----------------------------------
__global__ __launch_bounds__(256) void k_dec(const float* __restrict__ afx,
    const float* __restrict__ mu, const int* __restrict__ deg,
    const int2* __restrict__ buck, const unsigned short* __restrict__ WdT2,
    const float* __restrict__ wx, const float* __restrict__ sii_node,
    const int* __restrict__ flags, float* __restrict__ de,
    float* __restrict__ loss)
{
  __shared__ float stg[2][4][16][68];
  __shared__ float amuL[64][17];
  __shared__ float bsum[4];
  const int tid  = threadIdx.x;
  const int lane = tid & 63;
  const int wave = tid >> 6;
  const int base = blockIdx.x*64;

  // inline amu = A@mu for this block's 64 rows (16 rows x 16 lanes per pass)
  {
    int l = tid & 15, rg = tid >> 4;
    #pragma unroll
    for (int pass = 0; pass < 4; ++pass){
      int lr = pass*16 + rg;
      int row = base + lr;
      int d = deg[row]; if (d > 64) d = 64;
      const int2* bp = buck + ((size_t)row << 6);
      float acc = 0.f;
      for (int p = 0; p < d; ++p){
        int2 ce = bp[p];
        acc += __int_as_float(ce.y) * mu[(size_t)ce.x*16 + l];
      }
      amuL[lr][l] = acc;
    }
  }
  __syncthreads();

  const int r0 = base + wave*16;
  const int kg = lane >> 4;
  const int l15 = lane & 15;
  const int row = r0 + l15;
  f32x4 a0, a1;
  if (kg < 2){
    const float* asrc = afx + (size_t)row*16 + kg*8;
    a0 = *reinterpret_cast<const f32x4*>(asrc);
    a1 = *reinterpret_cast<const f32x4*>(asrc + 4);
  } else {
    const float* asrc = &amuL[wave*16 + l15][(kg-2)*8];
    a0 = *reinterpret_cast<const f32x4*>(asrc);
    a1 = *reinterpret_cast<const f32x4*>(asrc + 4);
  }
  bf16x8 af = cvt8(a0, a1);            // B-operand: az row (col of D-tile)
  const float* wsrc = wx + (size_t)row*32 + kg*8;
  f32x4 w0 = *reinterpret_cast<const f32x4*>(wsrc);
  f32x4 w1 = *reinterpret_cast<const f32x4*>(wsrc + 4);
  float sri = a0.x*w0.x + a0.y*w0.y + a0.z*w0.z + a0.w*w0.w
            + a1.x*w1.x + a1.y*w1.y + a1.z*w1.z + a1.w*w1.w;

  const f32x4 zero4 = {0.f,0.f,0.f,0.f};
  float sq = 0.f;
  const int srow = lane >> 4;            // 4 rows per store instr
  const int scol = l15*4;                // 16B segment within 64-col group

  for (int g = 0; g < 16; ++g){          // 16 groups of 64 cols (0..1023)
    int c0 = g*64;
    float (*S)[68] = stg[g&1][wave];     // per-wave double buffer: no tail drain
    #pragma unroll
    for (int j = 0; j < 4; ++j){
      int cb = c0 + j*16;
      bf16x8 bf = *reinterpret_cast<const bf16x8*>(&WdT2[(size_t)(cb + l15)*32 + kg*8]);
      // A-operand = Wdec^T frag; cols >=1000 are zero rows -> d = 0 (sq safe)
      f32x4 d = __builtin_amdgcn_mfma_f32_16x16x32_bf16(bf, af, zero4, 0, 0, 0);
      sq += d[0]*d[0] + d[1]*d[1] + d[2]*d[2] + d[3]*d[3];
      *reinterpret_cast<f32x4*>(&S[l15][j*16 + kg*4]) = d;
    }
    asm volatile("s_waitcnt lgkmcnt(0)" ::: "memory");
    __builtin_amdgcn_sched_barrier(0);
    #pragma unroll
    for (int sub = 0; sub < 4; ++sub){
      int lr = sub*4 + srow;
      int cc = c0 + scol;
      if (cc < Dd){
        f32x4 v = *reinterpret_cast<const f32x4*>(&S[lr][scol]);
        *reinterpret_cast<f32x4*>(&de[(size_t)(r0 + lr)*Dd + cc]) = v;
      }
    }
    __builtin_amdgcn_sched_barrier(0);
  }
  sq  += __shfl_xor(sq, 16);  sq  += __shfl_xor(sq, 32);
  sri += __shfl_xor(sri, 16); sri += __shfl_xor(sri, 32);
  float tval = 0.f;
  if (kg == 0){
    float nr = fmaxf(sqrtf(sq), 1e-12f);
    float ni = fmaxf(sqrtf(sii_node[row]), 1e-12f);
    float tt = 1.f - sri/(nr*ni);
    tval = flags[row] ? tt*tt*tt : 0.f;
  }
  #pragma unroll
  for (int o = 1; o < 16; o <<= 1) tval += __shfl_xor(tval, o);
  if (lane == 0) bsum[wave] = tval;
  __syncthreads();
  if (tid == 0)
    atomicAdd(loss, (bsum[0] + bsum[1] + bsum[2] + bsum[3]) * (1.f/MM));
}

// ---- launch ------------------------------------------------------------------
extern "C" void kernel_launch(void* const* d_in, const int* in_sizes, int n_in,
                              void* d_out, int out_size, void* d_ws, size_t ws_size,
                              hipStream_t stream)
{
  const float* x     = (const float*)d_in[0];
  const int*   erow  = (const int*)  d_in[1];
  const int*   ecol  = (const int*)  d_in[2];
  const float* evls  = (const float*)d_in[3];
  const int*   mask  = (const int*)  d_in[4];
  const float* token = (const float*)d_in[5];
  const float* W1  = (const float*)d_in[6];
  const float* b1  = (const float*)d_in[7];
  const float* g1  = (const float*)d_in[8];
  const float* be1 = (const float*)d_in[9];
  const float* rm1 = (const float*)d_in[10];
  const float* rv1 = (const float*)d_in[11];
  const float* W2  = (const float*)d_in[12];
  const float* b2  = (const float*)d_in[13];
  const float* g2  = (const float*)d_in[14];
  const float* be2 = (const float*)d_in[15];
  const float* rm2 = (const float*)d_in[16];
  const float* rv2 = (const float*)d_in[17];
  const float* Wgc1= (const float*)d_in[18];
  const float* Wgc2= (const float*)d_in[19];
  const float* Wgc3= (const float*)d_in[20];
  const float* Wdec= (const float*)d_in[21];
  const float* clus= (const float*)d_in[22];

  float* out = (float*)d_out;
  float* oz  = out;
  float* omu = out + (size_t)Nn*32;
  float* olv = omu + (size_t)Nn*16;
  float* ode = olv + (size_t)Nn*16;
  float* oq  = ode + (size_t)Nn*1000;
  float* ofx = oq  + (size_t)Nn*10;
  float* ogz = ofx + (size_t)Nn*16;
  float* olo = ogz + (size_t)Nn*16;

  char* w = (char*)d_ws;
  unsigned short* Wim  = (unsigned short*)w; w += (size_t)262144;      // 32*128*32*2
  unsigned short* WdT2 = (unsigned short*)w; w += (size_t)65536;       // 1024*32*2
  float* tw    = (float*)w; w += 512;
  int* flags   = (int*)w;   w += (size_t)Nn*4;
  int* deg     = (int*)w;   w += (size_t)Nn*4;
  int2* buck   = (int2*)w;  w += (size_t)Nn*64*8;                      // 41 MB
  float* afx   = (float*)w; w += (size_t)Nn*16*4;
  unsigned short* h1b = (unsigned short*)w; w += (size_t)Nn*64*2;
  float* wx    = (float*)w; w += (size_t)Nn*32*4;
  float* sii   = (float*)w; w += (size_t)Nn*4;

  k_init<<<dim3(665), dim3(256), 0, stream>>>(W1, Wdec, token, Wim, WdT2, tw,
      flags, deg, olo);
  k_flags<<<dim3((MM+255)/256), dim3(256), 0, stream>>>(mask, flags);
  k_gemm1<<<dim3(5625), dim3(256), 0, stream>>>(x, Wim, flags, tw, token,
      b1, g1, be1, rm1, rv1, W2, b2, g2, be2, rm2, rv2, ofx, wx, sii,
      erow, ecol, evls, deg, buck);
  k_spmm16<<<dim3(Nn/16), dim3(256), 0, stream>>>(deg, buck, ofx, afx, Wgc1, h1b);
  k_gcn2<<<dim3(Nn/16), dim3(256), 0, stream>>>(deg, buck, h1b, Wgc2, Wgc3,
      ofx, clus, oz, omu, olv, ogz, oq);
  k_dec<<<dim3(Nn/64), dim3(256), 0, stream>>>(afx, omu, deg, buck, WdT2,
      wx, sii, flags, ode, olo);
}

// Round 16
// 485.676 us; speedup vs baseline: 1.1318x; 1.0797x over previous
//
#include <hip/hip_runtime.h>
#include <hip/hip_bf16.h>
#include <math.h>

#define Nn 80000
#define Dd 1000
#define Ee 1280000
#define MM 64000
#define NT 32   // K tiles of 32

typedef __attribute__((ext_vector_type(8))) short bf16x8;
typedef __attribute__((ext_vector_type(4))) float f32x4;

__device__ inline unsigned short f2bf(float f){
  union { float f; unsigned u; } c; c.f = f;
  unsigned u = c.u;
  u += 0x7FFFu + ((u >> 16) & 1u);
  return (unsigned short)(u >> 16);
}
__device__ inline float bf2f(unsigned short s){
  return __uint_as_float(((unsigned)s) << 16);
}

__device__ __forceinline__ void gload16(const void* g, void* l){
  __builtin_amdgcn_global_load_lds(
      (const __attribute__((address_space(1))) void*)g,
      (__attribute__((address_space(3))) void*)l, 16, 0, 0);
}

__device__ __forceinline__ bf16x8 cvt8(f32x4 a, f32x4 b){
  union { __hip_bfloat162 h; unsigned u; } c0, c1, c2, c3;
  c0.h = __float22bfloat162_rn(make_float2(a.x, a.y));
  c1.h = __float22bfloat162_rn(make_float2(a.z, a.w));
  c2.h = __float22bfloat162_rn(make_float2(b.x, b.y));
  c3.h = __float22bfloat162_rn(make_float2(b.z, b.w));
  union { unsigned u[4]; bf16x8 v; } r;
  r.u[0] = c0.u; r.u[1] = c1.u; r.u[2] = c2.u; r.u[3] = c3.u;
  return r.v;
}

// ---- init: Wim compact swizzled B image; WdT2 (1024 rows, zero-padded);
//      tw[97]; zero flags/deg/loss --------------------------------------------
__global__ __launch_bounds__(256) void k_init(const float* __restrict__ W1,
    const float* __restrict__ Wdec, const float* __restrict__ token,
    unsigned short* __restrict__ Wim, unsigned short* __restrict__ WdT2,
    float* __restrict__ tw, int* __restrict__ flags, int* __restrict__ deg,
    float* __restrict__ loss)
{
  int i = blockIdx.x*256 + threadIdx.x;   // grid 665 blocks = 170240 threads
  if (i < 131072){                        // Wim: 32 tiles x 128 rows x 32 bf16
    int t   = i >> 12;
    int rem = i & 4095;
    int c   = rem >> 5;                   // row (col of W) 0..127
    int pos = rem & 31;
    int slot = pos >> 3;                  // 16B unit in LDS
    int j    = pos & 7;
    int u    = slot ^ (c & 3);            // pre-applied swizzle
    int k    = t*32 + u*8 + j;
    float v = 0.f;
    if (c < 96 && k < Dd) v = (c < 64) ? W1[k*64 + c] : Wdec[(size_t)(c-64)*Dd + k];
    Wim[i] = f2bf(v);
  }
  unsigned t1 = (unsigned)(i - 131072);
  if (t1 < 32768u){                       // WdT2[col][k] = Wdec[k][col], col<1024
    int col = t1 >> 5, k = t1 & 31;
    WdT2[t1] = (col < Dd) ? f2bf(Wdec[(size_t)k*Dd + col]) : (unsigned short)0;
  }
  if (i < Nn){ flags[i] = 0; deg[i] = 0; }
  if (i == 0) *loss = 0.f;
  unsigned u3 = (unsigned)(i - 163840);
  if (u3 < 6208u){                        // tw: one wave per output j
    int j = u3 >> 6, l = u3 & 63;
    float s = 0.f;
    if (j < 64){ for (int k = l; k < Dd; k += 64) s += token[k]*W1[k*64 + j]; }
    else if (j < 96){ const float* wr = Wdec + (size_t)(j-64)*Dd;
                      for (int k = l; k < Dd; k += 64) s += token[k]*wr[k]; }
    else { for (int k = l; k < Dd; k += 64) s += token[k]*token[k]; }
    #pragma unroll
    for (int o = 32; o; o >>= 1) s += __shfl_down(s, o);
    if (l == 0) tw[j] = s;
  }
}

// ---- flags scatter (must precede fused gemm which reads flags) --------------
__global__ __launch_bounds__(256) void k_flags(const int* __restrict__ mask,
    int* __restrict__ flags)
{
  int i = blockIdx.x*256 + threadIdx.x;
  if (i < MM) flags[mask[i]] = 1;
}

// ---- FUSED: blocks 0..624 = GEMM1 (reg-staged bf16 A); 625.. = edge fill ----
// LDS: As 0..8192 (bf16 [128][32] swizzled), B0 8192..16384, B1 16384..24576,
//      tokL 24576..28672. Phase2: Hs 0..33792, W2s 33792..37888.
__global__ __launch_bounds__(256, 4) void k_gemm1(
    const float* __restrict__ x, const unsigned short* __restrict__ Wim,
    const int* __restrict__ flags, const float* __restrict__ tw,
    const float* __restrict__ token,
    const float* __restrict__ b1, const float* __restrict__ g1,
    const float* __restrict__ be1, const float* __restrict__ rm1,
    const float* __restrict__ rv1, const float* __restrict__ W2,
    const float* __restrict__ b2, const float* __restrict__ g2,
    const float* __restrict__ be2, const float* __restrict__ rm2,
    const float* __restrict__ rv2, float* __restrict__ fx,
    float* __restrict__ wx, float* __restrict__ sii_node,
    const int* __restrict__ erow, const int* __restrict__ ecol,
    const float* __restrict__ evls, int* __restrict__ deg,
    int2* __restrict__ buck)
{
  __shared__ char smem[37888];
  if (blockIdx.x >= 625){                 // ---- edge-fill path ----
    int i = (blockIdx.x - 625)*256 + threadIdx.x;
    if (i < Ee){
      int r = erow[i];
      int s = atomicAdd(&deg[r], 1);
      if (s < 64){
        int2 pr; pr.x = ecol[i]; pr.y = __float_as_int(evls[i]);
        buck[((size_t)r << 6) + s] = pr;
      }
    }
    return;
  }
  // ---- GEMM path ----
  unsigned short* As = (unsigned short*)smem;
  float* tokL = (float*)(smem + 24576);
  const int tid  = threadIdx.x;
  const int lane = tid & 63;
  const int wave = tid >> 6;
  const int wm = wave >> 1, wn = wave & 1;
  const int l15 = lane & 15, kg = lane >> 4;
  const int row0 = blockIdx.x * 128;

  const int rtid = tid >> 3;              // staging row within group (0..31)
  const int kq   = (tid & 7) * 4;         // k-slice 0,4,..,28
  const int wu   = (kq >> 3) ^ (rtid & 3) ^ ((rtid >> 2) & 3);  // write swizzle
  const int wofs = rtid*32 + wu*8 + (kq & 4);

  const float* xbase = x + (size_t)row0 * Dd;
  f32x4 ra[4];

  for (int i = tid; i < 1024; i += 256) tokL[i] = (i < Dd) ? token[i] : 0.f;

  // prologue: issue A(0), B(0)
  {
    int col = kq;
    #pragma unroll
    for (int j = 0; j < 4; ++j)
      ra[j] = *(const f32x4*)(xbase + (size_t)(j*32 + rtid)*Dd + col);
    const char* wim = (const char*)Wim;
    gload16(wim + (wave*2  )*1024 + lane*16, smem + 8192 + (wave*2  )*1024);
    gload16(wim + (wave*2+1)*1024 + lane*16, smem + 8192 + (wave*2+1)*1024);
  }
  asm volatile("s_waitcnt lgkmcnt(0)" ::: "memory");
  __builtin_amdgcn_s_barrier();           // tokL visible

  const f32x4 zero4 = {0.f,0.f,0.f,0.f};
  f32x4 acc[4][3];
  #pragma unroll
  for (int i = 0; i < 4; ++i){ acc[i][0]=zero4; acc[i][1]=zero4; acc[i][2]=zero4; }
  float sx2[4] = {0.f,0.f,0.f,0.f};
  float sxt[4] = {0.f,0.f,0.f,0.f};

  #pragma unroll 2
  for (int t = 0; t < NT; ++t){
    const char* Bb = smem + 8192 + (t&1)*8192;
    const int k0 = t*32;
    const bool kok = (t < NT-1) || (kq <= 4);
    f32x4 tok4 = *(const f32x4*)(tokL + k0 + kq);

    // stage A(t): cvt once + sii partials + swizzled bf16 ds_write
    #pragma unroll
    for (int j = 0; j < 4; ++j){
      f32x4 v = ra[j];
      if (kok){
        sx2[j] += v.x*v.x + v.y*v.y + v.z*v.z + v.w*v.w;
        sxt[j] += v.x*tok4.x + v.y*tok4.y + v.z*tok4.z + v.w*tok4.w;
      }
      union { __hip_bfloat162 h; unsigned u; } c0, c1;
      c0.h = __float22bfloat162_rn(make_float2(v.x, v.y));
      c1.h = __float22bfloat162_rn(make_float2(v.z, v.w));
      uint2 pk; pk.x = c0.u; pk.y = c1.u;
      *reinterpret_cast<uint2*>(&As[j*1024 + wofs]) = pk;
    }

    // issue A(t+1), B(t+1)
    if (t + 1 < NT){
      int col = k0 + 32 + kq; if (col > 996) col = 996;
      #pragma unroll
      for (int j = 0; j < 4; ++j)
        ra[j] = *(const f32x4*)(xbase + (size_t)(j*32 + rtid)*Dd + col);
      const char* wim = (const char*)Wim + (size_t)(t+1)*8192;
      char* Bn = smem + 8192 + ((t+1)&1)*8192;
      gload16(wim + (wave*2  )*1024 + lane*16, Bn + (wave*2  )*1024);
      gload16(wim + (wave*2+1)*1024 + lane*16, Bn + (wave*2+1)*1024);
      asm volatile("s_waitcnt lgkmcnt(0)" ::: "memory");
      asm volatile("s_waitcnt vmcnt(6)" ::: "memory");
    } else {
      asm volatile("s_waitcnt lgkmcnt(0)" ::: "memory");
      asm volatile("s_waitcnt vmcnt(0)" ::: "memory");
    }
    __builtin_amdgcn_s_barrier();
    __builtin_amdgcn_sched_barrier(0);

    // MFMA phase
    bf16x8 bfr[3];
    #pragma unroll
    for (int ni = 0; ni < 3; ++ni){
      int c = wn*48 + ni*16 + l15;
      bfr[ni] = *(const bf16x8*)(Bb + c*64 + ((kg ^ (c & 3)) << 4));
    }
    const int ru = (kg ^ (l15 & 3) ^ ((l15 >> 2) & 3)) << 4;
    #pragma unroll
    for (int mi = 0; mi < 4; ++mi){
      int r = wm*64 + mi*16 + l15;
      bf16x8 af = *(const bf16x8*)((const char*)As + r*64 + ru);
      acc[mi][0] = __builtin_amdgcn_mfma_f32_16x16x32_bf16(af, bfr[0], acc[mi][0], 0, 0, 0);
      acc[mi][1] = __builtin_amdgcn_mfma_f32_16x16x32_bf16(af, bfr[1], acc[mi][1], 0, 0, 0);
      acc[mi][2] = __builtin_amdgcn_mfma_f32_16x16x32_bf16(af, bfr[2], acc[mi][2], 0, 0, 0);
    }
    __builtin_amdgcn_sched_barrier(0);
    __builtin_amdgcn_s_barrier();
  }

  // sii: 8-thread shfl reduce (threads 8r..8r+7 share a row)
  float stt = tw[96];
  #pragma unroll
  for (int j = 0; j < 4; ++j){
    float a2 = sx2[j], at = sxt[j];
    a2 += __shfl_xor(a2, 1); at += __shfl_xor(at, 1);
    a2 += __shfl_xor(a2, 2); at += __shfl_xor(at, 2);
    a2 += __shfl_xor(a2, 4); at += __shfl_xor(at, 4);
    if ((tid & 7) == 0){
      int row = row0 + j*32 + rtid;
      float fl = flags[row] ? 1.f : 0.f;
      sii_node[row] = a2 + fl*(2.f*at + stt);
    }
  }

  // per-output-row flags
  float flv[4][4];
  #pragma unroll
  for (int mi = 0; mi < 4; ++mi)
    #pragma unroll
    for (int r4 = 0; r4 < 4; ++r4)
      flv[mi][r4] = flags[row0 + wm*64 + mi*16 + (lane>>4)*4 + r4] ? 1.f : 0.f;

  float* Hs  = (float*)smem;
  float* W2s = (float*)(smem + 33792);
  for (int i = tid; i < 1024; i += 256) W2s[i] = W2[i];

  // epilogue: cols <64 -> BN1+ELU into Hs; cols >=64 -> wx
  #pragma unroll
  for (int ni = 0; ni < 3; ++ni){
    int n = wn*48 + ni*16 + l15;
    float twn = tw[n];
    if (n < 64){
      float bb = b1[n], rmv = rm1[n];
      float scv = g1[n]*rsqrtf(rv1[n] + 1e-3f), bev = be1[n];
      #pragma unroll
      for (int mi = 0; mi < 4; ++mi){
        #pragma unroll
        for (int r4 = 0; r4 < 4; ++r4){
          int lrow = wm*64 + mi*16 + (lane>>4)*4 + r4;
          float v = (acc[mi][ni][r4] + flv[mi][r4]*twn + bb - rmv)*scv + bev;
          v = (v > 0.f) ? v : expm1f(v);
          Hs[lrow*66 + n] = v;
        }
      }
    } else {
      int j = n - 64;
      #pragma unroll
      for (int mi = 0; mi < 4; ++mi){
        #pragma unroll
        for (int r4 = 0; r4 < 4; ++r4){
          int lrow = wm*64 + mi*16 + (lane>>4)*4 + r4;
          wx[(size_t)(row0 + lrow)*32 + j] = acc[mi][ni][r4] + flv[mi][r4]*twn;
        }
      }
    }
  }
  __syncthreads();

  // phase 2: fx = elu(bn2(Hs @ W2 + b2))
  {
    int j = tid & 15;
    float pb = b2[j], prm = rm2[j];
    float psc = g2[j]*rsqrtf(rv2[j] + 1e-3f), pbe = be2[j];
    int rb = (tid >> 4) * 8;
    #pragma unroll
    for (int rr = 0; rr < 8; ++rr){
      int r = rb + rr;
      float a = pb;
      #pragma unroll
      for (int k = 0; k < 64; ++k) a += Hs[r*66 + k]*W2s[k*16 + j];
      float v = (a - prm)*psc + pbe;
      v = (v > 0.f) ? v : expm1f(v);
      fx[(size_t)(row0 + r)*16 + j] = v;
    }
  }
}

// ---- SpMM F=16 over buckets + fused h1 = relu(row @ Wgc1) -> bf16 -----------
__global__ __launch_bounds__(256) void k_spmm16(const int* __restrict__ deg,
    const int2* __restrict__ buck, const float* __restrict__ in,
    float* __restrict__ out, const float* __restrict__ Wgc1,
    unsigned short* __restrict__ h1b)
{
  __shared__ float Ws[1024];
  for (int t = threadIdx.x; t < 1024; t += 256) Ws[t] = Wgc1[t];
  __syncthreads();
  int row = blockIdx.x*16 + (threadIdx.x >> 4);
  int l = threadIdx.x & 15;
  int d = deg[row]; if (d > 64) d = 64;
  const int2* bp = buck + ((size_t)row << 6);
  float acc = 0.f;
  for (int p = 0; p < d; ++p){
    int2 ce = bp[p];
    acc += __int_as_float(ce.y) * in[(size_t)ce.x*16 + l];
  }
  out[(size_t)row*16 + l] = acc;
  float h0=0.f, h1=0.f, h2=0.f, h3=0.f;
  #pragma unroll
  for (int k = 0; k < 16; ++k){
    float av = __shfl(acc, k, 16);
    const float* wp = &Ws[k*64 + l*4];
    h0 += av*wp[0]; h1 += av*wp[1]; h2 += av*wp[2]; h3 += av*wp[3];
  }
  ushort4 pk;
  pk.x = f2bf(fmaxf(h0, 0.f)); pk.y = f2bf(fmaxf(h1, 0.f));
  pk.z = f2bf(fmaxf(h2, 0.f)); pk.w = f2bf(fmaxf(h3, 0.f));
  *reinterpret_cast<ushort4*>(&h1b[(size_t)row*64 + l*4]) = pk;
}

// ---- GCN2: 16 rows/block; ah = A@h1 (bf16 gather), mu/lv/z/gz, fused q ------
__global__ __launch_bounds__(256) void k_gcn2(const int* __restrict__ deg,
    const int2* __restrict__ buck, const unsigned short* __restrict__ h1b,
    const float* __restrict__ Wgc2, const float* __restrict__ Wgc3,
    const float* __restrict__ fx, const float* __restrict__ cl,
    float* __restrict__ z, float* __restrict__ mu,
    float* __restrict__ lv, float* __restrict__ gz, float* __restrict__ q)
{
  __shared__ float ah[16][65];
  __shared__ float Ws[2048];
  __shared__ float cls[320];
  __shared__ float zs[16][33];
  __shared__ float qv[16][10];
  int t = threadIdx.x;
  for (int i = t; i < 1024; i += 256){ Ws[i] = Wgc2[i]; Ws[1024 + i] = Wgc3[i]; }
  for (int i = t; i < 320; i += 256) cls[i] = cl[i];
  const int wave = t >> 6, lane = t & 63;
  const int row0 = blockIdx.x*16;
  #pragma unroll
  for (int rr = 0; rr < 4; ++rr){
    int lr = wave*4 + rr;
    int row = row0 + lr;
    int d = deg[row]; if (d > 64) d = 64;
    const int2* bp = buck + ((size_t)row << 6);
    float acc = 0.f;
    for (int p = 0; p < d; ++p){
      int2 ce = bp[p];
      acc += __int_as_float(ce.y) * bf2f(h1b[(size_t)ce.x*64 + lane]);
    }
    ah[lr][lane] = acc;
  }
  __syncthreads();
  {
    int r = t >> 4, j = t & 15;
    const float* ar = ah[r];
    float m = 0.f, l = 0.f;
    #pragma unroll 16
    for (int k = 0; k < 64; ++k){
      float a = ar[k];
      m += a*Ws[k*16 + j];
      l += a*Ws[1024 + k*16 + j];
    }
    size_t grow = (size_t)(row0 + r);
    mu[grow*16 + j] = m;
    gz[grow*16 + j] = m;
    z[grow*32 + 16 + j] = m;
    zs[r][16 + j] = m;
    lv[grow*16 + j] = l;
    float v = fx[grow*16 + j];
    z[grow*32 + j] = v;
    zs[r][j] = v;
  }
  __syncthreads();
  if (t < 160){
    int r = t / 10, c = t - r*10;
    float d2 = 0.f;
    #pragma unroll
    for (int k = 0; k < 32; ++k){ float d = zs[r][k] - cls[c*32 + k]; d2 += d*d; }
    qv[r][c] = 1.f/(1.f + d2);
  }
  __syncthreads();
  if (t < 160){
    int r = t / 10, c = t - r*10;
    float ss = 0.f;
    #pragma unroll
    for (int cc = 0; cc < 10; ++cc) ss += qv[r][cc];
    q[(size_t)(row0 + r)*10 + c] = qv[r][c]/ss;
  }
}

// ---- decoder: inline amu gather + MFMA + LDS-bounce stores + fused loss -----
__global__ __launch_bounds__(256) void k_dec(const float* __restrict__ afx,
    const float* __restrict__ mu, const int* __restrict__ deg,
    const int2* __restrict__ buck, const unsigned short* __restrict__ WdT2,
    const float* __restrict__ wx, const float* __restrict__ sii_node,
    const int* __restrict__ flags, float* __restrict__ de,
    float* __restrict__ loss)
{
  __shared__ float stg[4][16][68];
  __shared__ float amuL[64][17];
  __shared__ float bsum[4];
  const int tid  = threadIdx.x;
  const int lane = tid & 63;
  const int wave = tid >> 6;
  const int base = blockIdx.x*64;

  // inline amu = A@mu for this block's 64 rows (16 rows x 16 lanes per pass)
  {
    int l = tid & 15, rg = tid >> 4;
    #pragma unroll
    for (int pass = 0; pass < 4; ++pass){
      int lr = pass*16 + rg;
      int row = base + lr;
      int d = deg[row]; if (d > 64) d = 64;
      const int2* bp = buck + ((size_t)row << 6);
      float acc = 0.f;
      for (int p = 0; p < d; ++p){
        int2 ce = bp[p];
        acc += __int_as_float(ce.y) * mu[(size_t)ce.x*16 + l];
      }
      amuL[lr][l] = acc;
    }
  }
  __syncthreads();

  const int r0 = base + wave*16;
  const int kg = lane >> 4;
  const int l15 = lane & 15;
  const int row = r0 + l15;
  f32x4 a0, a1;
  if (kg < 2){
    const float* asrc = afx + (size_t)row*16 + kg*8;
    a0 = *reinterpret_cast<const f32x4*>(asrc);
    a1 = *reinterpret_cast<const f32x4*>(asrc + 4);
  } else {
    const float* asrc = &amuL[wave*16 + l15][(kg-2)*8];
    a0 = *reinterpret_cast<const f32x4*>(asrc);
    a1 = *reinterpret_cast<const f32x4*>(asrc + 4);
  }
  bf16x8 af = cvt8(a0, a1);            // B-operand: az row (col of D-tile)
  const float* wsrc = wx + (size_t)row*32 + kg*8;
  f32x4 w0 = *reinterpret_cast<const f32x4*>(wsrc);
  f32x4 w1 = *reinterpret_cast<const f32x4*>(wsrc + 4);
  float sri = a0.x*w0.x + a0.y*w0.y + a0.z*w0.z + a0.w*w0.w
            + a1.x*w1.x + a1.y*w1.y + a1.z*w1.z + a1.w*w1.w;

  const f32x4 zero4 = {0.f,0.f,0.f,0.f};
  float sq = 0.f;
  float (*S)[68] = stg[wave];
  const int srow = lane >> 4;            // 4 rows per store instr
  const int scol = l15*4;                // 16B segment within 64-col group

  for (int g = 0; g < 16; ++g){          // 16 groups of 64 cols (0..1023)
    int c0 = g*64;
    #pragma unroll
    for (int j = 0; j < 4; ++j){
      int cb = c0 + j*16;
      bf16x8 bf = *reinterpret_cast<const bf16x8*>(&WdT2[(size_t)(cb + l15)*32 + kg*8]);
      // A-operand = Wdec^T frag; cols >=1000 are zero rows -> d = 0 (sq safe)
      f32x4 d = __builtin_amdgcn_mfma_f32_16x16x32_bf16(bf, af, zero4, 0, 0, 0);
      sq += d[0]*d[0] + d[1]*d[1] + d[2]*d[2] + d[3]*d[3];
      *reinterpret_cast<f32x4*>(&S[l15][j*16 + kg*4]) = d;
    }
    asm volatile("s_waitcnt lgkmcnt(0)" ::: "memory");
    __builtin_amdgcn_sched_barrier(0);
    #pragma unroll
    for (int sub = 0; sub < 4; ++sub){
      int lr = sub*4 + srow;
      int cc = c0 + scol;
      if (cc < Dd){
        f32x4 v = *reinterpret_cast<const f32x4*>(&S[lr][scol]);
        *reinterpret_cast<f32x4*>(&de[(size_t)(r0 + lr)*Dd + cc]) = v;
      }
    }
    __builtin_amdgcn_sched_barrier(0);
    asm volatile("s_waitcnt lgkmcnt(0)" ::: "memory");   // reads done before rewrite
  }
  sq  += __shfl_xor(sq, 16);  sq  += __shfl_xor(sq, 32);
  sri += __shfl_xor(sri, 16); sri += __shfl_xor(sri, 32);
  float tval = 0.f;
  if (kg == 0){
    float nr = fmaxf(sqrtf(sq), 1e-12f);
    float ni = fmaxf(sqrtf(sii_node[row]), 1e-12f);
    float tt = 1.f - sri/(nr*ni);
    tval = flags[row] ? tt*tt*tt : 0.f;
  }
  #pragma unroll
  for (int o = 1; o < 16; o <<= 1) tval += __shfl_xor(tval, o);
  if (lane == 0) bsum[wave] = tval;
  __syncthreads();
  if (tid == 0)
    atomicAdd(loss, (bsum[0] + bsum[1] + bsum[2] + bsum[3]) * (1.f/MM));
}

// ---- launch ------------------------------------------------------------------
extern "C" void kernel_launch(void* const* d_in, const int* in_sizes, int n_in,
                              void* d_out, int out_size, void* d_ws, size_t ws_size,
                              hipStream_t stream)
{
  const float* x     = (const float*)d_in[0];
  const int*   erow  = (const int*)  d_in[1];
  const int*   ecol  = (const int*)  d_in[2];
  const float* evls  = (const float*)d_in[3];
  const int*   mask  = (const int*)  d_in[4];
  const float* token = (const float*)d_in[5];
  const float* W1  = (const float*)d_in[6];
  const float* b1  = (const float*)d_in[7];
  const float* g1  = (const float*)d_in[8];
  const float* be1 = (const float*)d_in[9];
  const float* rm1 = (const float*)d_in[10];
  const float* rv1 = (const float*)d_in[11];
  const float* W2  = (const float*)d_in[12];
  const float* b2  = (const float*)d_in[13];
  const float* g2  = (const float*)d_in[14];
  const float* be2 = (const float*)d_in[15];
  const float* rm2 = (const float*)d_in[16];
  const float* rv2 = (const float*)d_in[17];
  const float* Wgc1= (const float*)d_in[18];
  const float* Wgc2= (const float*)d_in[19];
  const float* Wgc3= (const float*)d_in[20];
  const float* Wdec= (const float*)d_in[21];
  const float* clus= (const float*)d_in[22];

  float* out = (float*)d_out;
  float* oz  = out;
  float* omu = out + (size_t)Nn*32;
  float* olv = omu + (size_t)Nn*16;
  float* ode = olv + (size_t)Nn*16;
  float* oq  = ode + (size_t)Nn*1000;
  float* ofx = oq  + (size_t)Nn*10;
  float* ogz = ofx + (size_t)Nn*16;
  float* olo = ogz + (size_t)Nn*16;

  char* w = (char*)d_ws;
  unsigned short* Wim  = (unsigned short*)w; w += (size_t)262144;      // 32*128*32*2
  unsigned short* WdT2 = (unsigned short*)w; w += (size_t)65536;       // 1024*32*2
  float* tw    = (float*)w; w += 512;
  int* flags   = (int*)w;   w += (size_t)Nn*4;
  int* deg     = (int*)w;   w += (size_t)Nn*4;
  int2* buck   = (int2*)w;  w += (size_t)Nn*64*8;                      // 41 MB
  float* afx   = (float*)w; w += (size_t)Nn*16*4;
  unsigned short* h1b = (unsigned short*)w; w += (size_t)Nn*64*2;
  float* wx    = (float*)w; w += (size_t)Nn*32*4;
  float* sii   = (float*)w; w += (size_t)Nn*4;

  k_init<<<dim3(665), dim3(256), 0, stream>>>(W1, Wdec, token, Wim, WdT2, tw,
      flags, deg, olo);
  k_flags<<<dim3((MM+255)/256), dim3(256), 0, stream>>>(mask, flags);
  k_gemm1<<<dim3(5625), dim3(256), 0, stream>>>(x, Wim, flags, tw, token,
      b1, g1, be1, rm1, rv1, W2, b2, g2, be2, rm2, rv2, ofx, wx, sii,
      erow, ecol, evls, deg, buck);
  k_spmm16<<<dim3(Nn/16), dim3(256), 0, stream>>>(deg, buck, ofx, afx, Wgc1, h1b);
  k_gcn2<<<dim3(Nn/16), dim3(256), 0, stream>>>(deg, buck, h1b, Wgc2, Wgc3,
      ofx, clus, oz, omu, olv, ogz, oq);
  k_dec<<<dim3(Nn/64), dim3(256), 0, stream>>>(afx, omu, deg, buck, WdT2,
      wx, sii, flags, ode, olo);
}